// Round 7
// baseline (476.849 us; speedup 1.0000x reference)
//
#include <hip/hip_runtime.h>
#include <math.h>

// input (32,3,128,128) f32; output (32,3,512,512) f32.
// loss = mean |bicubic_down4(output) - input|, 16-tap separable, symmetric pad 6.
#define BCN   96
#define IN_H  512
#define IN_W  512
#define OUT_H 128
#define OUT_W 128
#define TAPS  16
#define PAD   6
#define STRIDE 4
#define TR    8
#define IR    ((TR - 1) * STRIDE + TAPS)   // 44 rows
#define NCH   (IR / 4)                     // 11 chunks of 4 rows
#define NBLK  (BCN * (OUT_H / TR))         // 1536 blocks
#define TOTAL_ELEMS (BCN * OUT_H * OUT_W)

struct K16 { float w[TAPS]; };

__device__ __forceinline__ int sym_idx(int i, int n) {
    i = (i < 0) ? (-1 - i) : i;
    return (i >= n) ? (2 * n - 1 - i) : i;
}

__device__ __forceinline__ int swz1(int b) { return b ^ (((b >> 7) & 1) << 4); }

// ---------------- diagnostic probe: pure deep-ILP read of 100 MB ------------
// 3072 blocks x 256 thr; thread t reads 8 independent float4 at t + k*786432.
// 786432*8 = 6291456 float4 = 100,663,296 B exactly.
#define PROBE_N4 6291456
__global__ __launch_bounds__(256)
void probe_read(const float4* __restrict__ src, float* __restrict__ sink)
{
    const int t = blockIdx.x * 256 + threadIdx.x;
    float4 v[8];
    #pragma unroll
    for (int k = 0; k < 8; ++k) v[k] = src[t + k * 786432];
    float acc = 0.f;
    #pragma unroll
    for (int k = 0; k < 8; ++k) acc += v[k].x + v[k].y + v[k].z + v[k].w;
    #pragma unroll
    for (int off = 32; off > 0; off >>= 1) acc += __shfl_down(acc, off, 64);
    if ((threadIdx.x & 63) == 0) atomicAdd(sink, acc);
}

// ---------------- real kernel: round-5 version (validated) ------------------
__global__ __launch_bounds__(256)
void bploss_kernel(const float* __restrict__ input,
                   const float* __restrict__ outimg,
                   float* __restrict__ loss, K16 kwa)
{
    __shared__ float dbuf[2][4 * IN_W];
    __shared__ float hrow[2][4][OUT_W];
    __shared__ float kwl[TAPS];
    __shared__ float wsum[4];

    const int tid  = threadIdx.x;
    const int bc   = blockIdx.x >> 4;
    const int tile = blockIdx.x & 15;
    const int r0   = tile * TR;
    const int iy0  = r0 * STRIDE - PAD;
    const float* img = outimg + (size_t)bc * IN_H * IN_W;

    auto gsrc = [&](int ch, int s) -> const float4* {
        const int y = sym_idx(iy0 + ch * 4 + (s >> 7), IN_H);
        return reinterpret_cast<const float4*>(img + (size_t)y * IN_W + (s & 127) * 4);
    };
    auto lslot = [&](float* buf, int s) -> float4* {
        return reinterpret_cast<float4*>(reinterpret_cast<char*>(buf) + swz1(s << 4));
    };

    if (tid < TAPS) kwl[tid] = kwa.w[tid];

    float4 rA[4], rB[4];
    #pragma unroll
    for (int c0 = 0; c0 < 3; ++c0) {
        rA[c0] = *gsrc(c0, tid);
        rB[c0] = *gsrc(c0, tid + 256);
    }
    *lslot(dbuf[0], tid)       = rA[0];
    *lslot(dbuf[0], tid + 256) = rB[0];
    asm volatile("s_waitcnt lgkmcnt(0)" ::: "memory");
    __builtin_amdgcn_s_barrier();
    __builtin_amdgcn_sched_barrier(0);

    const int pr = tid >> 6;
    const int c  = tid & 63;
    const int vb = tid >> 7;
    const int vx = tid & 127;
    int f0 = 8 * c - 8;
    f0 = (f0 < 0) ? 0 : (f0 > 488 ? 488 : f0);
    const int Lbase = pr * (IN_W * 4) + f0 * 4;
    float vacc[4] = {0.f, 0.f, 0.f, 0.f};

    #pragma unroll
    for (int i = 0; i < NCH; ++i) {
        if (i + 3 < NCH) {
            rA[(i + 3) & 3] = *gsrc(i + 3, tid);
            rB[(i + 3) & 3] = *gsrc(i + 3, tid + 256);
        }

        const char* raw = reinterpret_cast<const char*>(dbuf[i & 1]);
        const float4 w0 = *reinterpret_cast<const float4*>(raw + swz1(Lbase));
        const float4 w1 = *reinterpret_cast<const float4*>(raw + swz1(Lbase + 16));
        const float4 w2 = *reinterpret_cast<const float4*>(raw + swz1(Lbase + 32));
        const float4 w3 = *reinterpret_cast<const float4*>(raw + swz1(Lbase + 48));
        const float4 w4 = *reinterpret_cast<const float4*>(raw + swz1(Lbase + 64));
        const float4 w5 = *reinterpret_cast<const float4*>(raw + swz1(Lbase + 80));
        const float win[24] = { w0.x,w0.y,w0.z,w0.w, w1.x,w1.y,w1.z,w1.w,
                                w2.x,w2.y,w2.z,w2.w, w3.x,w3.y,w3.z,w3.w,
                                w4.x,w4.y,w4.z,w4.w, w5.x,w5.y,w5.z,w5.w };
        float acc0 = 0.f, acc1 = 0.f;
        #pragma unroll
        for (int t = 0; t < TAPS; ++t) {
            acc0 += kwa.w[t] * win[t + 2];
            acc1 += kwa.w[t] * win[t + 6];
        }
        if (c == 0) {
            float a0 = 0.f, a1 = 0.f;
            #pragma unroll
            for (int t = 0; t < TAPS; ++t) {
                const int i0 = (t < 6) ? (5 - t) : (t - 6);
                const int i1 = (t < 2) ? (1 - t) : (t - 2);
                a0 += kwa.w[t] * win[i0];
                a1 += kwa.w[t] * win[i1];
            }
            acc0 = a0; acc1 = a1;
        } else if (c == 63) {
            float a0 = 0.f, a1 = 0.f;
            #pragma unroll
            for (int t = 0; t < TAPS; ++t) {
                const int i0 = (t <= 13) ? (10 + t) : ((t == 14) ? 23 : 22);
                const int i1 = (t <= 9) ? (14 + t) : (33 - t);
                a0 += kwa.w[t] * win[i0];
                a1 += kwa.w[t] * win[i1];
            }
            acc0 = a0; acc1 = a1;
        }
        *reinterpret_cast<float2*>(&hrow[i & 1][pr][2 * c]) = make_float2(acc0, acc1);

        if (i + 1 < NCH) {
            *lslot(dbuf[(i + 1) & 1], tid)       = rA[(i + 1) & 3];
            *lslot(dbuf[(i + 1) & 1], tid + 256) = rB[(i + 1) & 3];
        }

        asm volatile("s_waitcnt lgkmcnt(0)" ::: "memory");
        __builtin_amdgcn_s_barrier();
        __builtin_amdgcn_sched_barrier(0);

        const float h0 = hrow[i & 1][0][vx], h1 = hrow[i & 1][1][vx],
                    h2 = hrow[i & 1][2][vx], h3 = hrow[i & 1][3][vx];
        #pragma unroll
        for (int k = 0; k < 4; ++k) {
            const int t0 = 4 * (i - (4 * vb + k));
            if (t0 >= 0 && t0 < TAPS) {
                vacc[k] += kwl[t0] * h0 + kwl[t0 + 1] * h1
                         + kwl[t0 + 2] * h2 + kwl[t0 + 3] * h3;
            }
        }
    }

    float lsum = 0.f;
    #pragma unroll
    for (int k = 0; k < 4; ++k) {
        const int yo = r0 + 4 * vb + k;
        const float ref = input[((size_t)bc * OUT_H + yo) * OUT_W + vx];
        lsum += fabsf(vacc[k] - ref);
    }
    #pragma unroll
    for (int off = 32; off > 0; off >>= 1)
        lsum += __shfl_down(lsum, off, 64);
    const int wid = tid >> 6, lane = tid & 63;
    if (lane == 0) wsum[wid] = lsum;
    __syncthreads();
    if (tid == 0) {
        const float s = wsum[0] + wsum[1] + wsum[2] + wsum[3];
        atomicAdd(loss, s * (1.0f / (float)TOTAL_ELEMS));
    }
}

static void make_weights(K16* kw) {
    const double scale = 0.25;
    double w[TAPS]; double s = 0.0;
    for (int t = 0; t < TAPS; ++t) {
        const double ax = fabs((7.5 - (double)t) * scale);
        double v;
        if (ax <= 1.0)      v = 1.5 * ax * ax * ax - 2.5 * ax * ax + 1.0;
        else if (ax <= 2.0) v = -0.5 * ax * ax * ax + 2.5 * ax * ax - 4.0 * ax + 2.0;
        else                v = 0.0;
        w[t] = v * scale; s += w[t];
    }
    for (int t = 0; t < TAPS; ++t) kw->w[t] = (float)(w[t] / s);
}

extern "C" void kernel_launch(void* const* d_in, const int* in_sizes, int n_in,
                              void* d_out, int out_size, void* d_ws, size_t ws_size,
                              hipStream_t stream) {
    const float* input;
    const float* outimg;
    if (in_sizes[0] == TOTAL_ELEMS) {
        input  = (const float*)d_in[0];
        outimg = (const float*)d_in[1];
    } else {
        input  = (const float*)d_in[1];
        outimg = (const float*)d_in[0];
    }
    float* loss = (float*)d_out;

    K16 kw;
    make_weights(&kw);

    // ---- diagnostic probes (results go to d_ws, never validated) ----
    // P1: ideal-pattern read of the 100 MB outimg input.
    // P2: identical pattern over 100 MB of d_ws (different allocation).
    if (ws_size >= (size_t)PROBE_N4 * 16 + 4096) {
        float* sink = (float*)d_ws;
        probe_read<<<3072, 256, 0, stream>>>(
            reinterpret_cast<const float4*>(outimg), sink);
        probe_read<<<3072, 256, 0, stream>>>(
            reinterpret_cast<const float4*>((char*)d_ws + 4096), sink + 1);
    }

    hipMemsetAsync(d_out, 0, sizeof(float), stream);
    bploss_kernel<<<NBLK, 256, 0, stream>>>(input, outimg, loss, kw);
}

// Round 8
// 158.611 us; speedup vs baseline: 3.0064x; 3.0064x over previous
//
#include <hip/hip_runtime.h>
#include <math.h>

// input (32,3,128,128) f32; output (32,3,512,512) f32.
// loss = mean |bicubic_down4(output) - input|, 16-tap separable, symmetric pad 6.
#define BCN   96
#define IN_H  512
#define IN_W  512
#define OUT_H 128
#define OUT_W 128
#define TAPS  16
#define PAD   6
#define STRIDE 4
#define TR    8
#define IR    ((TR - 1) * STRIDE + TAPS)   // 44 rows
#define NCH   (IR / 4)                     // 11 chunks of 4 rows
#define NBLK  (BCN * (OUT_H / TR))         // 1536 blocks
#define TOTAL_ELEMS (BCN * OUT_H * OUT_W)

struct K16 { float w[TAPS]; };

__device__ __forceinline__ int sym_idx(int i, int n) {
    i = (i < 0) ? (-1 - i) : i;
    return (i >= n) ? (2 * n - 1 - i) : i;
}

__device__ __forceinline__ int swz1(int b) { return b ^ (((b >> 7) & 1) << 4); }

// MODE 0: store per-block partial to d_ws (no atomic contention).
// MODE 1: legacy same-address atomicAdd fallback (only if ws too small).
template <int MODE>
__global__ __launch_bounds__(256)
void bploss_kernel(const float* __restrict__ input,
                   const float* __restrict__ outimg,
                   float* __restrict__ out,   // MODE0: partial[NBLK]; MODE1: loss
                   K16 kwa)
{
    __shared__ float dbuf[2][4 * IN_W];
    __shared__ float hrow[2][4][OUT_W];
    __shared__ float kwl[TAPS];
    __shared__ float wsum[4];

    const int tid  = threadIdx.x;
    const int bc   = blockIdx.x >> 4;
    const int tile = blockIdx.x & 15;
    const int r0   = tile * TR;
    const int iy0  = r0 * STRIDE - PAD;
    const float* img = outimg + (size_t)bc * IN_H * IN_W;

    auto gsrc = [&](int ch, int s) -> const float4* {
        const int y = sym_idx(iy0 + ch * 4 + (s >> 7), IN_H);
        return reinterpret_cast<const float4*>(img + (size_t)y * IN_W + (s & 127) * 4);
    };
    auto lslot = [&](float* buf, int s) -> float4* {
        return reinterpret_cast<float4*>(reinterpret_cast<char*>(buf) + swz1(s << 4));
    };

    if (tid < TAPS) kwl[tid] = kwa.w[tid];

    // 4-deep register prefetch pipeline (validated rounds 5-7)
    float4 rA[4], rB[4];
    #pragma unroll
    for (int c0 = 0; c0 < 3; ++c0) {
        rA[c0] = *gsrc(c0, tid);
        rB[c0] = *gsrc(c0, tid + 256);
    }
    *lslot(dbuf[0], tid)       = rA[0];
    *lslot(dbuf[0], tid + 256) = rB[0];
    asm volatile("s_waitcnt lgkmcnt(0)" ::: "memory");
    __builtin_amdgcn_s_barrier();
    __builtin_amdgcn_sched_barrier(0);

    const int pr = tid >> 6;
    const int c  = tid & 63;
    const int vb = tid >> 7;
    const int vx = tid & 127;
    int f0 = 8 * c - 8;
    f0 = (f0 < 0) ? 0 : (f0 > 488 ? 488 : f0);
    const int Lbase = pr * (IN_W * 4) + f0 * 4;
    float vacc[4] = {0.f, 0.f, 0.f, 0.f};

    #pragma unroll
    for (int i = 0; i < NCH; ++i) {
        if (i + 3 < NCH) {
            rA[(i + 3) & 3] = *gsrc(i + 3, tid);
            rB[(i + 3) & 3] = *gsrc(i + 3, tid + 256);
        }

        const char* raw = reinterpret_cast<const char*>(dbuf[i & 1]);
        const float4 w0 = *reinterpret_cast<const float4*>(raw + swz1(Lbase));
        const float4 w1 = *reinterpret_cast<const float4*>(raw + swz1(Lbase + 16));
        const float4 w2 = *reinterpret_cast<const float4*>(raw + swz1(Lbase + 32));
        const float4 w3 = *reinterpret_cast<const float4*>(raw + swz1(Lbase + 48));
        const float4 w4 = *reinterpret_cast<const float4*>(raw + swz1(Lbase + 64));
        const float4 w5 = *reinterpret_cast<const float4*>(raw + swz1(Lbase + 80));
        const float win[24] = { w0.x,w0.y,w0.z,w0.w, w1.x,w1.y,w1.z,w1.w,
                                w2.x,w2.y,w2.z,w2.w, w3.x,w3.y,w3.z,w3.w,
                                w4.x,w4.y,w4.z,w4.w, w5.x,w5.y,w5.z,w5.w };
        float acc0 = 0.f, acc1 = 0.f;
        #pragma unroll
        for (int t = 0; t < TAPS; ++t) {
            acc0 += kwa.w[t] * win[t + 2];
            acc1 += kwa.w[t] * win[t + 6];
        }
        if (c == 0) {          // f0=0: win[k] = col k (verified r2-r7)
            float a0 = 0.f, a1 = 0.f;
            #pragma unroll
            for (int t = 0; t < TAPS; ++t) {
                const int i0 = (t < 6) ? (5 - t) : (t - 6);
                const int i1 = (t < 2) ? (1 - t) : (t - 2);
                a0 += kwa.w[t] * win[i0];
                a1 += kwa.w[t] * win[i1];
            }
            acc0 = a0; acc1 = a1;
        } else if (c == 63) {  // f0=488: win[k] = col 488+k
            float a0 = 0.f, a1 = 0.f;
            #pragma unroll
            for (int t = 0; t < TAPS; ++t) {
                const int i0 = (t <= 13) ? (10 + t) : ((t == 14) ? 23 : 22);
                const int i1 = (t <= 9) ? (14 + t) : (33 - t);
                a0 += kwa.w[t] * win[i0];
                a1 += kwa.w[t] * win[i1];
            }
            acc0 = a0; acc1 = a1;
        }
        *reinterpret_cast<float2*>(&hrow[i & 1][pr][2 * c]) = make_float2(acc0, acc1);

        if (i + 1 < NCH) {
            *lslot(dbuf[(i + 1) & 1], tid)       = rA[(i + 1) & 3];
            *lslot(dbuf[(i + 1) & 1], tid + 256) = rB[(i + 1) & 3];
        }

        asm volatile("s_waitcnt lgkmcnt(0)" ::: "memory");
        __builtin_amdgcn_s_barrier();
        __builtin_amdgcn_sched_barrier(0);

        const float h0 = hrow[i & 1][0][vx], h1 = hrow[i & 1][1][vx],
                    h2 = hrow[i & 1][2][vx], h3 = hrow[i & 1][3][vx];
        #pragma unroll
        for (int k = 0; k < 4; ++k) {
            const int t0 = 4 * (i - (4 * vb + k));
            if (t0 >= 0 && t0 < TAPS) {
                vacc[k] += kwl[t0] * h0 + kwl[t0 + 1] * h1
                         + kwl[t0 + 2] * h2 + kwl[t0 + 3] * h3;
            }
        }
    }

    float lsum = 0.f;
    #pragma unroll
    for (int k = 0; k < 4; ++k) {
        const int yo = r0 + 4 * vb + k;
        const float ref = input[((size_t)bc * OUT_H + yo) * OUT_W + vx];
        lsum += fabsf(vacc[k] - ref);
    }
    #pragma unroll
    for (int off = 32; off > 0; off >>= 1)
        lsum += __shfl_down(lsum, off, 64);
    const int wid = tid >> 6, lane = tid & 63;
    if (lane == 0) wsum[wid] = lsum;
    __syncthreads();
    if (tid == 0) {
        const float s = wsum[0] + wsum[1] + wsum[2] + wsum[3];
        if (MODE == 0) out[blockIdx.x] = s;                       // plain store
        else atomicAdd(out, s * (1.0f / (float)TOTAL_ELEMS));     // fallback
    }
}

// single-block final reduction: 1536 partials -> loss
__global__ __launch_bounds__(256)
void reduce_kernel(const float* __restrict__ partial, float* __restrict__ loss)
{
    __shared__ float wsum[4];
    const int tid = threadIdx.x;
    float acc = 0.f;
    #pragma unroll
    for (int k = 0; k < NBLK / 256; ++k) acc += partial[tid + k * 256];
    #pragma unroll
    for (int off = 32; off > 0; off >>= 1) acc += __shfl_down(acc, off, 64);
    if ((tid & 63) == 0) wsum[tid >> 6] = acc;
    __syncthreads();
    if (tid == 0)
        loss[0] = (wsum[0] + wsum[1] + wsum[2] + wsum[3]) * (1.0f / (float)TOTAL_ELEMS);
}

static void make_weights(K16* kw) {
    const double scale = 0.25;
    double w[TAPS]; double s = 0.0;
    for (int t = 0; t < TAPS; ++t) {
        const double ax = fabs((7.5 - (double)t) * scale);
        double v;
        if (ax <= 1.0)      v = 1.5 * ax * ax * ax - 2.5 * ax * ax + 1.0;
        else if (ax <= 2.0) v = -0.5 * ax * ax * ax + 2.5 * ax * ax - 4.0 * ax + 2.0;
        else                v = 0.0;
        w[t] = v * scale; s += w[t];
    }
    for (int t = 0; t < TAPS; ++t) kw->w[t] = (float)(w[t] / s);
}

extern "C" void kernel_launch(void* const* d_in, const int* in_sizes, int n_in,
                              void* d_out, int out_size, void* d_ws, size_t ws_size,
                              hipStream_t stream) {
    const float* input;
    const float* outimg;
    if (in_sizes[0] == TOTAL_ELEMS) {
        input  = (const float*)d_in[0];
        outimg = (const float*)d_in[1];
    } else {
        input  = (const float*)d_in[1];
        outimg = (const float*)d_in[0];
    }
    float* loss = (float*)d_out;

    K16 kw;
    make_weights(&kw);

    if (ws_size >= (size_t)NBLK * sizeof(float)) {
        float* partial = (float*)d_ws;
        bploss_kernel<0><<<NBLK, 256, 0, stream>>>(input, outimg, partial, kw);
        reduce_kernel<<<1, 256, 0, stream>>>(partial, loss);
    } else {
        hipMemsetAsync(d_out, 0, sizeof(float), stream);
        bploss_kernel<1><<<NBLK, 256, 0, stream>>>(input, outimg, loss, kw);
    }
}